// Round 5
// baseline (36.887 us; speedup 1.0000x reference)
//
#include <hip/hip_runtime.h>

// SimplestSpline: out[b,c,h,w] = piecewise-linear(raw[b,c,h,w]; params[b, c*16..])
// raw: (8,3,1024,1024) fp32 in [0,1]; params: (8,48) fp32.
// 17 uniform segments on [0,1]; knot values padded with 0 (left) and 1 (right).
//
// R1: exact-cover grid, loads hoisted for MLP.              (35.4 us)
// R3: NT stores — regression, reverted.                     (36.7 us)
// R4: (a) wave-private LDS table -> NO __syncthreads, so no compiler-forced
//         vmcnt(0) drain at block start; (b) global loads issued BEFORE table
//         init so load latency hides under init; (c) 3072 x 256 x 8 exact cover.

#define N_KNOTS 16
#define N_SEG 17           // N_KNOTS + 1
#define N_B 8
#define N_C 3
#define N_BC 24            // N_B * N_C
#define N_TAB (N_BC * N_SEG)   // 408 entries
#define LOG2_HW4 18        // log2(1024*1024 / 4) — float4s per (b,c) plane

#define BLOCK 256
#define WAVES (BLOCK / 64)
#define GRID 3072
#define ITERS 8            // GRID*BLOCK*ITERS == 6291456 == B*C*H*W/4

typedef float floatx4 __attribute__((ext_vector_type(4)));

__global__ __launch_bounds__(BLOCK) void spline_kernel(
    const float* __restrict__ raw,
    const float* __restrict__ params,
    float* __restrict__ out)
{
    // One private table per wave: no inter-wave dependency -> no barrier.
    __shared__ float2 tab[WAVES][N_TAB];   // 4 * 408 * 8 B = 13056 B

    const int lane = threadIdx.x & 63;
    const int wid  = threadIdx.x >> 6;

    const int base   = blockIdx.x * BLOCK + threadIdx.x;
    const int stride = GRID * BLOCK;   // 786,432 float4s

    const floatx4* __restrict__ in4  = reinterpret_cast<const floatx4*>(raw);
    floatx4* __restrict__       out4 = reinterpret_cast<floatx4*>(out);

    // (b) Issue ALL global loads first — latency hides under table init.
    floatx4 x4[ITERS];
    #pragma unroll
    for (int k = 0; k < ITERS; ++k)
        x4[k] = in4[base + k * stride];

    // (a) Wave-private table build: entry t = (bc, seg);
    //     .x = y_right(seg), .y = slope(seg).
    #pragma unroll
    for (int t = lane; t < N_TAB; t += 64) {
        int bc  = t / N_SEG;
        int seg = t - bc * N_SEG;
        int b   = bc / N_C;
        int c   = bc - b * N_C;
        const float* p = params + b * (N_C * N_KNOTS) + c * N_KNOTS;
        float yl = (seg == 0)         ? 0.0f : p[seg - 1];
        float yr = (seg == N_SEG - 1) ? 1.0f : p[seg];
        float2 e;
        e.x = yr;
        e.y = (yr - yl) * 17.0f;      // slope = diff/dx, dx = 1/17
        tab[wid][t] = e;
    }
    // No __syncthreads: each wave reads only its own copy; compiler orders
    // ds_write -> ds_read with fine-grained lgkmcnt.

    const float dx = 1.0f / 17.0f;

    #pragma unroll
    for (int k = 0; k < ITERS; ++k) {
        const int i  = base + k * stride;
        const int bc = i >> LOG2_HW4;
        const float2* wtab = &tab[wid][bc * N_SEG];

        floatx4 o;
        #pragma unroll
        for (int j = 0; j < 4; ++j) {
            float x = x4[k][j];
            int idx = (int)floorf(x * 17.0f);
            idx = max(0, min(idx, N_SEG - 1));
            float2 e = wtab[idx];               // ds_read_b64, conflict-light
            float xs_r = (float)(idx + 1) * dx; // right knot x
            o[j] = fmaf(x - xs_r, e.y, e.x);    // == y_right - (xs_r - x)*slope
        }
        out4[i] = o;                            // normal store (NT regressed)
    }
}

extern "C" void kernel_launch(void* const* d_in, const int* in_sizes, int n_in,
                              void* d_out, int out_size, void* d_ws, size_t ws_size,
                              hipStream_t stream) {
    const float* raw    = (const float*)d_in[0];
    const float* params = (const float*)d_in[1];
    float* out          = (float*)d_out;

    spline_kernel<<<GRID, BLOCK, 0, stream>>>(raw, params, out);
}

// Round 6
// 35.170 us; speedup vs baseline: 1.0488x; 1.0488x over previous
//
#include <hip/hip_runtime.h>

// SimplestSpline: out[b,c,h,w] = piecewise-linear(raw[b,c,h,w]; params[b, c*16..])
// raw: (8,3,1024,1024) fp32 in [0,1]; params: (8,48) fp32.
// 17 uniform segments on [0,1]; knot values padded with 0 (left) and 1 (right).
//
// R1: exact-cover grid, shared LDS table + 1 barrier, loads hoisted. (35.4 us)
// R3: NT stores — regression (nt does not avoid L3 write-allocate).  (36.7 us)
// R4: wave-private tables — regression (4x init work, longer chain). (36.9 us)
// R5: back to R1 structure; table holds (c0, slope) with c0 = y_r - x_r*s so
//     the per-element epilogue is a single fma(x, s, c0); idx via trunc-cvt
//     (x>=0); GRID=8192 x ITERS=3 for smoother ramp/tail.

#define N_KNOTS 16
#define N_SEG 17           // N_KNOTS + 1
#define N_B 8
#define N_C 3
#define N_BC 24            // N_B * N_C
#define LOG2_HW4 18        // log2(1024*1024 / 4) — float4s per (b,c) plane

#define BLOCK 256
#define GRID 8192
#define ITERS 3            // GRID*BLOCK*ITERS == 6291456 == B*C*H*W/4

typedef float floatx4 __attribute__((ext_vector_type(4)));

__global__ __launch_bounds__(BLOCK) void spline_kernel(
    const float* __restrict__ raw,
    const float* __restrict__ params,
    float* __restrict__ out)
{
    // Per-segment table: .x = c0 = y_right - x_right*slope, .y = slope.
    // out = fma(x, slope, c0)  ==  y_right - (x_right - x)*slope (to ~1 ulp).
    __shared__ float2 tab[N_BC][N_SEG];   // 24*17*8 B = 3264 B

    for (int t = threadIdx.x; t < N_BC * N_SEG; t += BLOCK) {
        int bc  = t / N_SEG;
        int seg = t - bc * N_SEG;
        int b   = bc / N_C;
        int c   = bc - b * N_C;
        const float* p = params + b * (N_C * N_KNOTS) + c * N_KNOTS;
        float yl = (seg == 0)         ? 0.0f : p[seg - 1];
        float yr = (seg == N_SEG - 1) ? 1.0f : p[seg];
        float s  = (yr - yl) * 17.0f;             // slope = diff/dx, dx = 1/17
        float xr = (float)(seg + 1) * (1.0f / 17.0f);
        float2 e;
        e.x = fmaf(-xr, s, yr);                   // c0
        e.y = s;
        tab[bc][seg] = e;
    }
    __syncthreads();

    const int base   = blockIdx.x * BLOCK + threadIdx.x;
    const int stride = GRID * BLOCK;   // 2,097,152 float4s

    const floatx4* __restrict__ in4  = reinterpret_cast<const floatx4*>(raw);
    floatx4* __restrict__       out4 = reinterpret_cast<floatx4*>(out);

    // Issue all loads up-front (static indices -> stays in VGPRs).
    floatx4 x4[ITERS];
    #pragma unroll
    for (int k = 0; k < ITERS; ++k)
        x4[k] = in4[base + k * stride];

    #pragma unroll
    for (int k = 0; k < ITERS; ++k) {
        const int i  = base + k * stride;
        const int bc = i >> LOG2_HW4;

        floatx4 o;
        #pragma unroll
        for (int j = 0; j < 4; ++j) {
            float x = x4[k][j];
            int idx = (int)(x * 17.0f);          // trunc == floor (x >= 0)
            idx = min(idx, N_SEG - 1);           // only x == 1.0 needs the clamp
            float2 e = tab[bc][idx];             // one ds_read_b64
            o[j] = fmaf(x, e.y, e.x);            // slope*x + c0
        }
        out4[i] = o;
    }
}

extern "C" void kernel_launch(void* const* d_in, const int* in_sizes, int n_in,
                              void* d_out, int out_size, void* d_ws, size_t ws_size,
                              hipStream_t stream) {
    const float* raw    = (const float*)d_in[0];
    const float* params = (const float*)d_in[1];
    float* out          = (float*)d_out;

    spline_kernel<<<GRID, BLOCK, 0, stream>>>(raw, params, out);
}